// Round 1
// baseline (812.994 us; speedup 1.0000x reference)
//
#include <hip/hip_runtime.h>
#include <math.h>

typedef __bf16 bf16;
typedef __bf16 bf16x8 __attribute__((ext_vector_type(8)));
typedef __bf16 bf16x4v __attribute__((ext_vector_type(4)));
typedef float f32x4 __attribute__((ext_vector_type(4)));

#define NB 4
#define NT 2048
#define NC 2048
#define NH 16
#define ND 128
#define NROW (NB*NT)   // 8192

#define GLD16(g, l) __builtin_amdgcn_global_load_lds( \
    (__attribute__((address_space(1))) void*)(g), \
    (__attribute__((address_space(3))) void*)(l), 16, 0, 0)

// ---------------- fp32 -> bf16 convert ----------------
__global__ void cvt_kernel(const float* __restrict__ in, bf16* __restrict__ out, int n4) {
  int stride = gridDim.x * blockDim.x;
  for (int i = blockIdx.x * blockDim.x + threadIdx.x; i < n4; i += stride) {
    float4 v = reinterpret_cast<const float4*>(in)[i];
    bf16x4v o;
    o[0] = (bf16)v.x; o[1] = (bf16)v.y; o[2] = (bf16)v.z; o[3] = (bf16)v.w;
    reinterpret_cast<bf16x4v*>(out)[i] = o;
  }
}

// ---------------- omega = sigmoid((x . w_omega + b)/16), one block per row ----------------
__global__ void omega_kernel(const float* __restrict__ x, const float* __restrict__ w_om,
                             const float* __restrict__ b_om, float* __restrict__ omega) {
  int row = blockIdx.x;
  const float4* xr = reinterpret_cast<const float4*>(x + (size_t)row * NC);
  const float4* wr = reinterpret_cast<const float4*>(w_om);
  float sum = 0.f;
  for (int i = threadIdx.x; i < NC/4; i += 256) {
    float4 a = xr[i], b = wr[i];
    sum += a.x*b.x + a.y*b.y + a.z*b.z + a.w*b.w;
  }
  for (int m = 32; m; m >>= 1) sum += __shfl_xor(sum, m);
  __shared__ float wsum[4];
  if ((threadIdx.x & 63) == 0) wsum[threadIdx.x >> 6] = sum;
  __syncthreads();
  if (threadIdx.x == 0) {
    float d = wsum[0] + wsum[1] + wsum[2] + wsum[3] + b_om[0];
    omega[row] = 1.f / (1.f + expf(-d * (1.f/16.f)));
  }
}

// ---------------- exclusive cumsum over T per batch (fp64 accumulation) ----------------
__global__ void scan_kernel(const float* __restrict__ omega, float* __restrict__ phi) {
  int b = blockIdx.x;
  const float* om = omega + (size_t)b * NT;
  float* ph = phi + (size_t)b * NT;
  int t = threadIdx.x;
  float v[8]; float s = 0.f;
  #pragma unroll
  for (int j = 0; j < 8; j++) { v[j] = om[t*8 + j]; s += v[j]; }
  __shared__ float totals[256];
  __shared__ double base_sh[256];
  totals[t] = s;
  __syncthreads();
  if (t == 0) {
    double run = 0.0;
    for (int i = 0; i < 256; i++) { base_sh[i] = run; run += (double)totals[i]; }
  }
  __syncthreads();
  double run = base_sh[t];
  #pragma unroll
  for (int j = 0; j < 8; j++) { ph[t*8 + j] = (float)run; run += (double)v[j]; }
}

// ---------------- cos/sin table: [row][dd], dd in 0..63 ----------------
__global__ void sincos_kernel(const float* __restrict__ phi, const float* __restrict__ log_freq,
                              float* __restrict__ cos_t, float* __restrict__ sin_t) {
  int i = blockIdx.x * 256 + threadIdx.x;   // < NROW*64
  int row = i >> 6, dd = i & 63;
  float f = expf(log_freq[dd]);
  float a = phi[row] * f;
  float si, co;
  sincosf(a, &si, &co);
  cos_t[i] = co;
  sin_t[i] = si;
}

// ---------------- GEMM: C[m][n] = sum_k A[m][k]*B[n][k]  (both row-major, K-contiguous) -----
// MODE 0: rotate+rmsnorm epilogue, bf16 out (q/k projections)
// MODE 1: plain bf16 out (v projection)
// MODE 2: plain fp32 out (output projection)
template<int MODE>
__global__ __launch_bounds__(256, 2)
void gemm_bt(const bf16* __restrict__ A, const bf16* __restrict__ Bm,
             void* __restrict__ Cout,
             const float* __restrict__ cos_t, const float* __restrict__ sin_t,
             const float* __restrict__ gamma) {
  constexpr int K = NC;
  __shared__ bf16 Als[128*32];
  __shared__ bf16 Bls[128*32];
  const int t = threadIdx.x;
  const int w = t >> 6, lane = t & 63, lg = lane >> 4, l15 = lane & 15;
  const int m0 = blockIdx.y * 128, n0 = blockIdx.x * 128;

  const bf16* Asrc = A + (size_t)(m0 + (t >> 2)) * K + (t & 3) * 8;
  const bf16* Bsrc = Bm + (size_t)(n0 + (t >> 2)) * K + (t & 3) * 8;
  bf16* AdstL = &Als[w * 512];
  bf16* AdstH = &Als[2048 + w * 512];
  bf16* BdstL = &Bls[w * 512];
  bf16* BdstH = &Bls[2048 + w * 512];

  f32x4 acc[2][8] = {};

  for (int kt = 0; kt < K; kt += 32) {
    GLD16(Asrc + kt, AdstL);
    GLD16(Asrc + (size_t)64 * K + kt, AdstH);
    GLD16(Bsrc + kt, BdstL);
    GLD16(Bsrc + (size_t)64 * K + kt, BdstH);
    __syncthreads();
    bf16x8 af[2], bfr[8];
    #pragma unroll
    for (int mt = 0; mt < 2; mt++)
      af[mt] = *reinterpret_cast<const bf16x8*>(&Als[(w*32 + mt*16 + l15) * 32 + lg*8]);
    #pragma unroll
    for (int nt = 0; nt < 8; nt++)
      bfr[nt] = *reinterpret_cast<const bf16x8*>(&Bls[(nt*16 + l15) * 32 + lg*8]);
    #pragma unroll
    for (int mt = 0; mt < 2; mt++)
      #pragma unroll
      for (int nt = 0; nt < 8; nt++)
        acc[mt][nt] = __builtin_amdgcn_mfma_f32_16x16x32_bf16(af[mt], bfr[nt], acc[mt][nt], 0, 0, 0);
    __syncthreads();
  }

  if constexpr (MODE == 0) {
    bf16* out = (bf16*)Cout;
    #pragma unroll
    for (int mt = 0; mt < 2; mt++) {
      #pragma unroll
      for (int r = 0; r < 4; r++) {
        int m = m0 + w*32 + mt*16 + lg*4 + r;
        float ss = 0.f;
        #pragma unroll
        for (int nt = 0; nt < 8; nt++) { float v = acc[mt][nt][r]; ss += v*v; }
        ss += __shfl_xor(ss, 1); ss += __shfl_xor(ss, 2);
        ss += __shfl_xor(ss, 4); ss += __shfl_xor(ss, 8);
        float scale = rsqrtf(ss * (1.f/128.f) + 1e-5f);
        size_t rowb = (size_t)m * NC + n0;
        size_t tabb = (size_t)m * 64;
        #pragma unroll
        for (int nt = 0; nt < 4; nt++) {
          int dd = nt*16 + l15;
          float c = cos_t[tabb + dd];
          float s = sin_t[tabb + dd];
          float t1 = acc[mt][nt][r], t2 = acc[mt][nt+4][r];
          float o1 = (t1*c + t2*s) * scale * gamma[dd];
          float o2 = (t2*c - t1*s) * scale * gamma[dd + 64];
          out[rowb + nt*16 + l15] = (bf16)o1;
          out[rowb + (nt+4)*16 + l15] = (bf16)o2;
        }
      }
    }
  } else {
    #pragma unroll
    for (int mt = 0; mt < 2; mt++) {
      #pragma unroll
      for (int r = 0; r < 4; r++) {
        int m = m0 + w*32 + mt*16 + lg*4 + r;
        size_t rowb = (size_t)m * NC + n0;
        #pragma unroll
        for (int nt = 0; nt < 8; nt++) {
          if constexpr (MODE == 1)
            ((bf16*)Cout)[rowb + nt*16 + l15] = (bf16)acc[mt][nt][r];
          else
            ((float*)Cout)[rowb + nt*16 + l15] = acc[mt][nt][r];
        }
      }
    }
  }
}

// ---------------- causal flash attention ----------------
// grid: (T/64, B*H), block 256 (4 waves, 16 q-rows each), KV tile = 32
__global__ __launch_bounds__(256, 2)
void fa_kernel(const bf16* __restrict__ Qg, const bf16* __restrict__ Kg,
               const bf16* __restrict__ Vg, bf16* __restrict__ Og) {
  __shared__ bf16 Kls[32 * 136];   // [kv][d], padded row 136 elems
  __shared__ bf16 Vls[128 * 40];   // [d][kv], padded row 40 elems (transposed)
  __shared__ bf16 Pls[4 * 16 * 32];
  const int t = threadIdx.x, w = t >> 6, lane = t & 63, lg = lane >> 4, l15 = lane & 15;
  const int qb = blockIdx.x, bh = blockIdx.y;
  const int b = bh >> 4, h = bh & 15;
  const size_t base = ((size_t)b * NT) * NC + (size_t)h * ND;
  const int q0 = qb * 64 + w * 16;

  bf16x8 qf[4];
  #pragma unroll
  for (int kc = 0; kc < 4; kc++)
    qf[kc] = *reinterpret_cast<const bf16x8*>(Qg + base + (size_t)(q0 + l15) * NC + kc*32 + lg*8);

  f32x4 oacc[8] = {};
  float m_run[4] = {-1e30f, -1e30f, -1e30f, -1e30f};
  float l_run[4] = {0.f, 0.f, 0.f, 0.f};
  const int nTile = (qb + 1) * 2;
  const float sc = 0.088388347648318447f;   // 1/sqrt(128)

  // K staging map: row t>>3 (0..31), col (t&7)*16  (coalesced, b128 LDS writes)
  const int ksrow = t >> 3, kscol = (t & 7) * 16;
  // V staging map: kv t&31, col (t>>5)*16  (spreads LDS banks on transpose writes)
  const int vkv = t & 31, vcol = (t >> 5) * 16;

  for (int kt = 0; kt < nTile; kt++) {
    const int kv0 = kt * 32;
    const bf16* kp = Kg + base + (size_t)(kv0 + ksrow) * NC + kscol;
    const bf16* vp = Vg + base + (size_t)(kv0 + vkv) * NC + vcol;
    bf16x8 ka = *reinterpret_cast<const bf16x8*>(kp);
    bf16x8 kb2 = *reinterpret_cast<const bf16x8*>(kp + 8);
    bf16x8 va = *reinterpret_cast<const bf16x8*>(vp);
    bf16x8 vb2 = *reinterpret_cast<const bf16x8*>(vp + 8);
    *reinterpret_cast<bf16x8*>(&Kls[ksrow * 136 + kscol]) = ka;
    *reinterpret_cast<bf16x8*>(&Kls[ksrow * 136 + kscol + 8]) = kb2;
    #pragma unroll
    for (int i = 0; i < 8; i++) {
      Vls[(vcol + i) * 40 + vkv] = va[i];
      Vls[(vcol + 8 + i) * 40 + vkv] = vb2[i];
    }
    __syncthreads();

    // S = Q K^T  (two 16-wide kv tiles)
    f32x4 s0 = {}, s1 = {};
    #pragma unroll
    for (int kc = 0; kc < 4; kc++) {
      bf16x8 k0 = *reinterpret_cast<const bf16x8*>(&Kls[l15 * 136 + kc*32 + lg*8]);
      bf16x8 k1 = *reinterpret_cast<const bf16x8*>(&Kls[(16 + l15) * 136 + kc*32 + lg*8]);
      s0 = __builtin_amdgcn_mfma_f32_16x16x32_bf16(qf[kc], k0, s0, 0, 0, 0);
      s1 = __builtin_amdgcn_mfma_f32_16x16x32_bf16(qf[kc], k1, s1, 0, 0, 0);
    }

    float al[4];
    #pragma unroll
    for (int r = 0; r < 4; r++) {
      int qrow = q0 + lg*4 + r;
      float v0 = s0[r] * sc, v1 = s1[r] * sc;
      if (kv0 + l15 > qrow) v0 = -1e30f;
      if (kv0 + 16 + l15 > qrow) v1 = -1e30f;
      float tm = fmaxf(v0, v1);
      tm = fmaxf(tm, __shfl_xor(tm, 1));
      tm = fmaxf(tm, __shfl_xor(tm, 2));
      tm = fmaxf(tm, __shfl_xor(tm, 4));
      tm = fmaxf(tm, __shfl_xor(tm, 8));
      float mn = fmaxf(m_run[r], tm);
      float a = __expf(m_run[r] - mn);
      float p0 = __expf(v0 - mn), p1 = __expf(v1 - mn);
      float rs = p0 + p1;
      rs += __shfl_xor(rs, 1); rs += __shfl_xor(rs, 2);
      rs += __shfl_xor(rs, 4); rs += __shfl_xor(rs, 8);
      l_run[r] = l_run[r] * a + rs;
      m_run[r] = mn;
      al[r] = a;
      Pls[w*512 + (lg*4 + r)*32 + l15] = (bf16)p0;
      Pls[w*512 + (lg*4 + r)*32 + 16 + l15] = (bf16)p1;
    }
    #pragma unroll
    for (int dt = 0; dt < 8; dt++) {
      f32x4 o = oacc[dt];
      o[0] *= al[0]; o[1] *= al[1]; o[2] *= al[2]; o[3] *= al[3];
      oacc[dt] = o;
    }
    bf16x8 pf = *reinterpret_cast<const bf16x8*>(&Pls[w*512 + l15*32 + lg*8]);
    #pragma unroll
    for (int dt = 0; dt < 8; dt++) {
      bf16x8 vf = *reinterpret_cast<const bf16x8*>(&Vls[(dt*16 + l15) * 40 + lg*8]);
      oacc[dt] = __builtin_amdgcn_mfma_f32_16x16x32_bf16(pf, vf, oacc[dt], 0, 0, 0);
    }
    __syncthreads();
  }

  #pragma unroll
  for (int r = 0; r < 4; r++) {
    float inv = 1.f / l_run[r];
    size_t orow = base + (size_t)(q0 + lg*4 + r) * NC;
    #pragma unroll
    for (int dt = 0; dt < 8; dt++)
      Og[orow + dt*16 + l15] = (bf16)(oacc[dt][r] * inv);
  }
}

// ---------------- host launch ----------------
extern "C" void kernel_launch(void* const* d_in, const int* in_sizes, int n_in,
                              void* d_out, int out_size, void* d_ws, size_t ws_size,
                              hipStream_t stream) {
  (void)in_sizes; (void)n_in; (void)out_size; (void)ws_size;
  const float* x       = (const float*)d_in[0];
  const float* Wq      = (const float*)d_in[1];
  const float* Wk      = (const float*)d_in[2];
  const float* Wv      = (const float*)d_in[3];
  const float* Wo      = (const float*)d_in[4];
  const float* w_omega = (const float*)d_in[5];
  const float* b_omega = (const float*)d_in[6];
  const float* log_freq= (const float*)d_in[7];
  const float* q_gamma = (const float*)d_in[8];
  const float* k_gamma = (const float*)d_in[9];

  char* p = (char*)d_ws;
  auto alloc = [&](size_t bytes) { void* r = (void*)p; p += (bytes + 255) & ~(size_t)255; return r; };
  bf16* xb   = (bf16*)alloc((size_t)NROW * NC * 2);
  bf16* wqb  = (bf16*)alloc((size_t)NC * NC * 2);
  bf16* wkb  = (bf16*)alloc((size_t)NC * NC * 2);
  bf16* wvb  = (bf16*)alloc((size_t)NC * NC * 2);
  bf16* wob  = (bf16*)alloc((size_t)NC * NC * 2);
  bf16* qb   = (bf16*)alloc((size_t)NROW * NC * 2);
  bf16* kb   = (bf16*)alloc((size_t)NROW * NC * 2);
  bf16* vb   = (bf16*)alloc((size_t)NROW * NC * 2);
  bf16* ob   = (bf16*)alloc((size_t)NROW * NC * 2);
  float* omega = (float*)alloc((size_t)NROW * 4);
  float* phi   = (float*)alloc((size_t)NROW * 4);
  float* cos_t = (float*)alloc((size_t)NROW * 64 * 4);
  float* sin_t = (float*)alloc((size_t)NROW * 64 * 4);

  cvt_kernel<<<4096, 256, 0, stream>>>(x, xb, NROW * NC / 4);
  cvt_kernel<<<2048, 256, 0, stream>>>(Wq, wqb, NC * NC / 4);
  cvt_kernel<<<2048, 256, 0, stream>>>(Wk, wkb, NC * NC / 4);
  cvt_kernel<<<2048, 256, 0, stream>>>(Wv, wvb, NC * NC / 4);
  cvt_kernel<<<2048, 256, 0, stream>>>(Wo, wob, NC * NC / 4);
  omega_kernel<<<NROW, 256, 0, stream>>>(x, w_omega, b_omega, omega);
  scan_kernel<<<NB, 256, 0, stream>>>(omega, phi);
  sincos_kernel<<<NROW * 64 / 256, 256, 0, stream>>>(phi, log_freq, cos_t, sin_t);

  dim3 gg(NC / 128, NROW / 128);
  gemm_bt<0><<<gg, 256, 0, stream>>>(xb, wqb, qb, cos_t, sin_t, q_gamma);
  gemm_bt<0><<<gg, 256, 0, stream>>>(xb, wkb, kb, cos_t, sin_t, k_gamma);
  gemm_bt<1><<<gg, 256, 0, stream>>>(xb, wvb, vb, nullptr, nullptr, nullptr);

  fa_kernel<<<dim3(NT / 64, NB * NH), 256, 0, stream>>>(qb, kb, vb, ob);

  gemm_bt<2><<<gg, 256, 0, stream>>>(ob, wob, d_out, nullptr, nullptr, nullptr);
}

// Round 2
// 584.380 us; speedup vs baseline: 1.3912x; 1.3912x over previous
//
#include <hip/hip_runtime.h>
#include <math.h>

typedef __bf16 bf16;
typedef __bf16 bf16x8 __attribute__((ext_vector_type(8)));
typedef __bf16 bf16x4v __attribute__((ext_vector_type(4)));
typedef float f32x4 __attribute__((ext_vector_type(4)));

#define NB 4
#define NT 2048
#define NC 2048
#define NH 16
#define ND 128
#define NROW (NB*NT)   // 8192

#define GLD16(g, l) __builtin_amdgcn_global_load_lds( \
    (__attribute__((address_space(1))) void*)(g), \
    (__attribute__((address_space(3))) void*)(l), 16, 0, 0)

// ---------------- fp32 -> bf16 convert ----------------
__global__ void cvt_kernel(const float* __restrict__ in, bf16* __restrict__ out, int n4) {
  int stride = gridDim.x * blockDim.x;
  for (int i = blockIdx.x * blockDim.x + threadIdx.x; i < n4; i += stride) {
    float4 v = reinterpret_cast<const float4*>(in)[i];
    bf16x4v o;
    o[0] = (bf16)v.x; o[1] = (bf16)v.y; o[2] = (bf16)v.z; o[3] = (bf16)v.w;
    reinterpret_cast<bf16x4v*>(out)[i] = o;
  }
}

// ---------------- omega = sigmoid((x . w_omega + b)/16), one block per row ----------------
__global__ void omega_kernel(const float* __restrict__ x, const float* __restrict__ w_om,
                             const float* __restrict__ b_om, float* __restrict__ omega) {
  int row = blockIdx.x;
  const float4* xr = reinterpret_cast<const float4*>(x + (size_t)row * NC);
  const float4* wr = reinterpret_cast<const float4*>(w_om);
  float sum = 0.f;
  for (int i = threadIdx.x; i < NC/4; i += 256) {
    float4 a = xr[i], b = wr[i];
    sum += a.x*b.x + a.y*b.y + a.z*b.z + a.w*b.w;
  }
  for (int m = 32; m; m >>= 1) sum += __shfl_xor(sum, m);
  __shared__ float wsum[4];
  if ((threadIdx.x & 63) == 0) wsum[threadIdx.x >> 6] = sum;
  __syncthreads();
  if (threadIdx.x == 0) {
    float d = wsum[0] + wsum[1] + wsum[2] + wsum[3] + b_om[0];
    omega[row] = 1.f / (1.f + expf(-d * (1.f/16.f)));
  }
}

// ---------------- exclusive cumsum over T per batch (fp64 accumulation) ----------------
__global__ void scan_kernel(const float* __restrict__ omega, float* __restrict__ phi) {
  int b = blockIdx.x;
  const float* om = omega + (size_t)b * NT;
  float* ph = phi + (size_t)b * NT;
  int t = threadIdx.x;
  float v[8]; float s = 0.f;
  #pragma unroll
  for (int j = 0; j < 8; j++) { v[j] = om[t*8 + j]; s += v[j]; }
  __shared__ float totals[256];
  __shared__ double base_sh[256];
  totals[t] = s;
  __syncthreads();
  if (t == 0) {
    double run = 0.0;
    for (int i = 0; i < 256; i++) { base_sh[i] = run; run += (double)totals[i]; }
  }
  __syncthreads();
  double run = base_sh[t];
  #pragma unroll
  for (int j = 0; j < 8; j++) { ph[t*8 + j] = (float)run; run += (double)v[j]; }
}

// ---------------- cos/sin table: [row][dd], dd in 0..63 ----------------
__global__ void sincos_kernel(const float* __restrict__ phi, const float* __restrict__ log_freq,
                              float* __restrict__ cos_t, float* __restrict__ sin_t) {
  int i = blockIdx.x * 256 + threadIdx.x;   // < NROW*64
  int row = i >> 6, dd = i & 63;
  float f = expf(log_freq[dd]);
  float a = phi[row] * f;
  float si, co;
  sincosf(a, &si, &co);
  cos_t[i] = co;
  sin_t[i] = si;
}

// ---------------- GEMM: C[m][n] = sum_k A[m][k]*B[n][k]  (both row-major, K-contiguous) -----
// MODE 0: rotate+rmsnorm epilogue, bf16 out (q/k projections)
// MODE 1: bf16 out, written TRANSPOSED per head: Vt[b][h][d][t]
// MODE 2: plain fp32 out (output projection)
template<int MODE>
__global__ __launch_bounds__(256, 2)
void gemm_bt(const bf16* __restrict__ A, const bf16* __restrict__ Bm,
             void* __restrict__ Cout,
             const float* __restrict__ cos_t, const float* __restrict__ sin_t,
             const float* __restrict__ gamma) {
  constexpr int K = NC;
  __shared__ bf16 Als[128*32];
  __shared__ bf16 Bls[128*32];
  const int t = threadIdx.x;
  const int w = t >> 6, lane = t & 63, lg = lane >> 4, l15 = lane & 15;
  const int m0 = blockIdx.y * 128, n0 = blockIdx.x * 128;

  const bf16* Asrc = A + (size_t)(m0 + (t >> 2)) * K + (t & 3) * 8;
  const bf16* Bsrc = Bm + (size_t)(n0 + (t >> 2)) * K + (t & 3) * 8;
  bf16* AdstL = &Als[w * 512];
  bf16* AdstH = &Als[2048 + w * 512];
  bf16* BdstL = &Bls[w * 512];
  bf16* BdstH = &Bls[2048 + w * 512];

  f32x4 acc[2][8] = {};

  for (int kt = 0; kt < K; kt += 32) {
    GLD16(Asrc + kt, AdstL);
    GLD16(Asrc + (size_t)64 * K + kt, AdstH);
    GLD16(Bsrc + kt, BdstL);
    GLD16(Bsrc + (size_t)64 * K + kt, BdstH);
    __syncthreads();
    bf16x8 af[2], bfr[8];
    #pragma unroll
    for (int mt = 0; mt < 2; mt++)
      af[mt] = *reinterpret_cast<const bf16x8*>(&Als[(w*32 + mt*16 + l15) * 32 + lg*8]);
    #pragma unroll
    for (int nt = 0; nt < 8; nt++)
      bfr[nt] = *reinterpret_cast<const bf16x8*>(&Bls[(nt*16 + l15) * 32 + lg*8]);
    #pragma unroll
    for (int mt = 0; mt < 2; mt++)
      #pragma unroll
      for (int nt = 0; nt < 8; nt++)
        acc[mt][nt] = __builtin_amdgcn_mfma_f32_16x16x32_bf16(af[mt], bfr[nt], acc[mt][nt], 0, 0, 0);
    __syncthreads();
  }

  if constexpr (MODE == 0) {
    bf16* out = (bf16*)Cout;
    #pragma unroll
    for (int mt = 0; mt < 2; mt++) {
      #pragma unroll
      for (int r = 0; r < 4; r++) {
        int m = m0 + w*32 + mt*16 + lg*4 + r;
        float ss = 0.f;
        #pragma unroll
        for (int nt = 0; nt < 8; nt++) { float v = acc[mt][nt][r]; ss += v*v; }
        ss += __shfl_xor(ss, 1); ss += __shfl_xor(ss, 2);
        ss += __shfl_xor(ss, 4); ss += __shfl_xor(ss, 8);
        float scale = rsqrtf(ss * (1.f/128.f) + 1e-5f);
        size_t rowb = (size_t)m * NC + n0;
        size_t tabb = (size_t)m * 64;
        #pragma unroll
        for (int nt = 0; nt < 4; nt++) {
          int dd = nt*16 + l15;
          float c = cos_t[tabb + dd];
          float s = sin_t[tabb + dd];
          float t1 = acc[mt][nt][r], t2 = acc[mt][nt+4][r];
          float o1 = (t1*c + t2*s) * scale * gamma[dd];
          float o2 = (t2*c - t1*s) * scale * gamma[dd + 64];
          out[rowb + nt*16 + l15] = (bf16)o1;
          out[rowb + (nt+4)*16 + l15] = (bf16)o2;
        }
      }
    }
  } else if constexpr (MODE == 1) {
    // transposed write: Vt[b][h][d][t], t fastest
    bf16* vt = (bf16*)Cout;
    const int h = n0 >> 7;   // one 128-wide block == one head
    #pragma unroll
    for (int mt = 0; mt < 2; mt++) {
      #pragma unroll
      for (int r = 0; r < 4; r++) {
        int m = m0 + w*32 + mt*16 + lg*4 + r;
        int bidx = m >> 11, tt = m & (NT-1);
        size_t hb = (((size_t)bidx * NH + h) * ND) * NT + tt;
        #pragma unroll
        for (int nt = 0; nt < 8; nt++) {
          int d = nt*16 + l15;
          vt[hb + (size_t)d * NT] = (bf16)acc[mt][nt][r];
        }
      }
    }
  } else {
    #pragma unroll
    for (int mt = 0; mt < 2; mt++) {
      #pragma unroll
      for (int r = 0; r < 4; r++) {
        int m = m0 + w*32 + mt*16 + lg*4 + r;
        size_t rowb = (size_t)m * NC + n0;
        #pragma unroll
        for (int nt = 0; nt < 8; nt++)
          ((float*)Cout)[rowb + nt*16 + l15] = acc[mt][nt][r];
      }
    }
  }
}

// ---------------- causal flash attention v2 ----------------
// grid: (B*H, T/128), block 256 (4 waves x 32 q-rows), KV tile = 64
// K LDS [64][128] linear+XOR-swizzled (staged via global_load_lds, pre-swizzled src)
// V LDS [128][64] from globally-transposed Vt, same staging trick
__global__ __launch_bounds__(256, 2)
void fa_kernel(const bf16* __restrict__ Qg, const bf16* __restrict__ Kg,
               const bf16* __restrict__ Vt, bf16* __restrict__ Og) {
  __shared__ bf16 Kls[64 * 128];
  __shared__ bf16 Vls[128 * 64];
  __shared__ bf16 Pls[4][32 * 68];   // per-wave P [q][kv], stride 68 elems (136B)
  const int t = threadIdx.x, w = t >> 6, lane = t & 63, lg = lane >> 4, l15 = lane & 15;
  const int bh = blockIdx.x;
  const int qb = (gridDim.y - 1) - blockIdx.y;   // big blocks dispatch first
  const size_t qkbase = (size_t)(bh >> 4) * NT * NC + (size_t)(bh & 15) * ND;
  const size_t vbase  = (size_t)bh * ND * NT;
  const int q0 = qb * 128 + w * 32;
  const float sc2 = 0.12751743f;   // log2(e)/sqrt(128)

  // Q fragments: rows q0 + mt*16 + l15, channel chunk kc*32 + lg*8
  bf16x8 qf[2][4];
  #pragma unroll
  for (int mt = 0; mt < 2; mt++)
    #pragma unroll
    for (int kc = 0; kc < 4; kc++)
      qf[mt][kc] = *reinterpret_cast<const bf16x8*>(
          Qg + qkbase + (size_t)(q0 + mt*16 + l15) * NC + kc*32 + lg*8);

  f32x4 oacc[2][8] = {};
  float m_run[2][4], l_run[2][4];
  #pragma unroll
  for (int mt = 0; mt < 2; mt++)
    #pragma unroll
    for (int r = 0; r < 4; r++) { m_run[mt][r] = -1e30f; l_run[mt][r] = 0.f; }

  // staging address precompute (XOR-swizzled source, linear LDS dest)
  const int kinS = ((t & 15) * 16) ^ (((t >> 4) & 7) << 4);
  const char* ksrc0 = (const char*)(Kg + qkbase) + (size_t)(t >> 4) * (NC*2) + kinS;
  char* kdst0 = (char*)Kls + t * 16;
  const int vinS = ((t & 7) * 16) ^ (((t >> 3) & 7) << 4);
  const char* vsrc0 = (const char*)(Vt + vbase) + (size_t)(t >> 3) * (NT*2) + vinS;
  char* vdst0 = (char*)Vls + t * 16;

  const int nfull = 2 * qb;          // unmasked tiles
  const int ntiles = 2 * qb + 2;

  for (int kt = 0; kt < ntiles; kt++) {
    const int kv0 = kt * 64;
    __syncthreads();   // previous tile's LDS reads complete
    {
      const char* ks = ksrc0 + (size_t)kv0 * (NC*2);
      const char* vs = vsrc0 + kv0 * 2;
      #pragma unroll
      for (int i = 0; i < 4; i++) {
        GLD16(ks + (size_t)i * 16 * NC * 2, kdst0 + i * 4096);
        GLD16(vs + (size_t)i * 32 * NT * 2, vdst0 + i * 4096);
      }
    }
    __syncthreads();   // staging landed

    if (q0 + 31 >= kv0) {
      // ---- S = Q K^T ----
      f32x4 s[2][4] = {};
      __builtin_amdgcn_s_setprio(1);
      #pragma unroll
      for (int kc = 0; kc < 4; kc++) {
        bf16x8 kf[4];
        const int swz = ((kc*64 + lg*16) ^ ((l15 & 7) << 4));
        #pragma unroll
        for (int nt = 0; nt < 4; nt++)
          kf[nt] = *reinterpret_cast<const bf16x8*>((const char*)Kls + (nt*16 + l15) * 256 + swz);
        #pragma unroll
        for (int mt = 0; mt < 2; mt++)
          #pragma unroll
          for (int nt = 0; nt < 4; nt++)
            s[mt][nt] = __builtin_amdgcn_mfma_f32_16x16x32_bf16(qf[mt][kc], kf[nt], s[mt][nt], 0, 0, 0);
      }
      __builtin_amdgcn_s_setprio(0);

      // ---- scale (+mask on diagonal tiles) ----
      #pragma unroll
      for (int mt = 0; mt < 2; mt++)
        #pragma unroll
        for (int nt = 0; nt < 4; nt++) {
          f32x4 v = s[mt][nt];
          v[0] *= sc2; v[1] *= sc2; v[2] *= sc2; v[3] *= sc2;
          s[mt][nt] = v;
        }
      if (kt >= nfull) {
        #pragma unroll
        for (int mt = 0; mt < 2; mt++)
          #pragma unroll
          for (int nt = 0; nt < 4; nt++) {
            int kv = kv0 + nt*16 + l15;
            #pragma unroll
            for (int r = 0; r < 4; r++)
              if (kv > q0 + mt*16 + lg*4 + r) s[mt][nt][r] = -1e30f;
          }
      }

      // ---- row maxima ----
      float tmax[2][4];
      #pragma unroll
      for (int mt = 0; mt < 2; mt++)
        #pragma unroll
        for (int r = 0; r < 4; r++) {
          float tm = fmaxf(fmaxf(s[mt][0][r], s[mt][1][r]), fmaxf(s[mt][2][r], s[mt][3][r]));
          tm = fmaxf(tm, __shfl_xor(tm, 1));
          tm = fmaxf(tm, __shfl_xor(tm, 2));
          tm = fmaxf(tm, __shfl_xor(tm, 4));
          tm = fmaxf(tm, __shfl_xor(tm, 8));
          tmax[mt][r] = tm;
        }

      // ---- defer-rescale (THR=0: exact) ----
      int ok = 1;
      #pragma unroll
      for (int mt = 0; mt < 2; mt++)
        #pragma unroll
        for (int r = 0; r < 4; r++) ok &= (tmax[mt][r] <= m_run[mt][r]);
      if (!__all(ok)) {
        #pragma unroll
        for (int mt = 0; mt < 2; mt++) {
          f32x4 alv;
          #pragma unroll
          for (int r = 0; r < 4; r++) {
            float mn = fmaxf(m_run[mt][r], tmax[mt][r]);
            float a = exp2f(m_run[mt][r] - mn);
            m_run[mt][r] = mn;
            l_run[mt][r] *= a;
            alv[r] = a;
          }
          #pragma unroll
          for (int dt = 0; dt < 8; dt++) {
            f32x4 o = oacc[mt][dt];
            o[0] *= alv[0]; o[1] *= alv[1]; o[2] *= alv[2]; o[3] *= alv[3];
            oacc[mt][dt] = o;
          }
        }
      }

      // ---- P = exp2(s - m), row sums, P -> LDS ----
      bf16* pw = &Pls[w][0];
      #pragma unroll
      for (int mt = 0; mt < 2; mt++)
        #pragma unroll
        for (int r = 0; r < 4; r++) {
          float p0 = exp2f(s[mt][0][r] - m_run[mt][r]);
          float p1 = exp2f(s[mt][1][r] - m_run[mt][r]);
          float p2 = exp2f(s[mt][2][r] - m_run[mt][r]);
          float p3 = exp2f(s[mt][3][r] - m_run[mt][r]);
          float rs = (p0 + p1) + (p2 + p3);
          rs += __shfl_xor(rs, 1); rs += __shfl_xor(rs, 2);
          rs += __shfl_xor(rs, 4); rs += __shfl_xor(rs, 8);
          l_run[mt][r] += rs;
          int qrow = mt*16 + lg*4 + r;
          pw[qrow*68 +      l15] = (bf16)p0;
          pw[qrow*68 + 16 + l15] = (bf16)p1;
          pw[qrow*68 + 32 + l15] = (bf16)p2;
          pw[qrow*68 + 48 + l15] = (bf16)p3;
        }

      // ---- O += P V ----
      bf16x8 pf[2][2];
      #pragma unroll
      for (int mt = 0; mt < 2; mt++)
        #pragma unroll
        for (int kc2 = 0; kc2 < 2; kc2++)
          pf[mt][kc2] = *reinterpret_cast<const bf16x8*>(
              (const char*)pw + (mt*16 + l15) * 136 + kc2*64 + lg*16);
      __builtin_amdgcn_s_setprio(1);
      #pragma unroll
      for (int kc2 = 0; kc2 < 2; kc2++) {
        const int swz = ((kc2*64 + lg*16) ^ ((l15 & 7) << 4));
        #pragma unroll
        for (int dt = 0; dt < 8; dt++) {
          bf16x8 vf = *reinterpret_cast<const bf16x8*>((const char*)Vls + (dt*16 + l15) * 128 + swz);
          #pragma unroll
          for (int mt = 0; mt < 2; mt++)
            oacc[mt][dt] = __builtin_amdgcn_mfma_f32_16x16x32_bf16(pf[mt][kc2], vf, oacc[mt][dt], 0, 0, 0);
        }
      }
      __builtin_amdgcn_s_setprio(0);
    }
  }

  // ---- epilogue ----
  #pragma unroll
  for (int mt = 0; mt < 2; mt++)
    #pragma unroll
    for (int r = 0; r < 4; r++) {
      float inv = 1.f / l_run[mt][r];
      size_t orow = qkbase + (size_t)(q0 + mt*16 + lg*4 + r) * NC;
      #pragma unroll
      for (int dt = 0; dt < 8; dt++)
        Og[orow + dt*16 + l15] = (bf16)(oacc[mt][dt][r] * inv);
    }
}

// ---------------- host launch ----------------
extern "C" void kernel_launch(void* const* d_in, const int* in_sizes, int n_in,
                              void* d_out, int out_size, void* d_ws, size_t ws_size,
                              hipStream_t stream) {
  (void)in_sizes; (void)n_in; (void)out_size; (void)ws_size;
  const float* x       = (const float*)d_in[0];
  const float* Wq      = (const float*)d_in[1];
  const float* Wk      = (const float*)d_in[2];
  const float* Wv      = (const float*)d_in[3];
  const float* Wo      = (const float*)d_in[4];
  const float* w_omega = (const float*)d_in[5];
  const float* b_omega = (const float*)d_in[6];
  const float* log_freq= (const float*)d_in[7];
  const float* q_gamma = (const float*)d_in[8];
  const float* k_gamma = (const float*)d_in[9];

  char* p = (char*)d_ws;
  auto alloc = [&](size_t bytes) { void* r = (void*)p; p += (bytes + 255) & ~(size_t)255; return r; };
  bf16* xb   = (bf16*)alloc((size_t)NROW * NC * 2);
  bf16* wqb  = (bf16*)alloc((size_t)NC * NC * 2);
  bf16* wkb  = (bf16*)alloc((size_t)NC * NC * 2);
  bf16* wvb  = (bf16*)alloc((size_t)NC * NC * 2);
  bf16* wob  = (bf16*)alloc((size_t)NC * NC * 2);
  bf16* qb   = (bf16*)alloc((size_t)NROW * NC * 2);
  bf16* kb   = (bf16*)alloc((size_t)NROW * NC * 2);
  bf16* vt   = (bf16*)alloc((size_t)NROW * NC * 2);  // transposed V: [B][H][D][T]
  bf16* ob   = (bf16*)alloc((size_t)NROW * NC * 2);
  float* omega = (float*)alloc((size_t)NROW * 4);
  float* phi   = (float*)alloc((size_t)NROW * 4);
  float* cos_t = (float*)alloc((size_t)NROW * 64 * 4);
  float* sin_t = (float*)alloc((size_t)NROW * 64 * 4);

  cvt_kernel<<<4096, 256, 0, stream>>>(x, xb, NROW * NC / 4);
  cvt_kernel<<<2048, 256, 0, stream>>>(Wq, wqb, NC * NC / 4);
  cvt_kernel<<<2048, 256, 0, stream>>>(Wk, wkb, NC * NC / 4);
  cvt_kernel<<<2048, 256, 0, stream>>>(Wv, wvb, NC * NC / 4);
  cvt_kernel<<<2048, 256, 0, stream>>>(Wo, wob, NC * NC / 4);
  omega_kernel<<<NROW, 256, 0, stream>>>(x, w_omega, b_omega, omega);
  scan_kernel<<<NB, 256, 0, stream>>>(omega, phi);
  sincos_kernel<<<NROW * 64 / 256, 256, 0, stream>>>(phi, log_freq, cos_t, sin_t);

  dim3 gg(NC / 128, NROW / 128);
  gemm_bt<0><<<gg, 256, 0, stream>>>(xb, wqb, qb, cos_t, sin_t, q_gamma);
  gemm_bt<0><<<gg, 256, 0, stream>>>(xb, wkb, kb, cos_t, sin_t, k_gamma);
  gemm_bt<1><<<gg, 256, 0, stream>>>(xb, wvb, vt, nullptr, nullptr, nullptr);

  fa_kernel<<<dim3(NB * NH, NT / 128), 256, 0, stream>>>(qb, kb, vt, ob);

  gemm_bt<2><<<gg, 256, 0, stream>>>(ob, wob, d_out, nullptr, nullptr, nullptr);
}

// Round 3
// 530.098 us; speedup vs baseline: 1.5337x; 1.1024x over previous
//
#include <hip/hip_runtime.h>
#include <math.h>

typedef __bf16 bf16;
typedef __bf16 bf16x8 __attribute__((ext_vector_type(8)));
typedef __bf16 bf16x4v __attribute__((ext_vector_type(4)));
typedef float f32x4 __attribute__((ext_vector_type(4)));

#define NB 4
#define NT 2048
#define NC 2048
#define NH 16
#define ND 128
#define NROW (NB*NT)   // 8192

#define GLD16(g, l) __builtin_amdgcn_global_load_lds( \
    (__attribute__((address_space(1))) void*)(g), \
    (__attribute__((address_space(3))) void*)(l), 16, 0, 0)

// ---------------- fp32 -> bf16 convert ----------------
__global__ void cvt_kernel(const float* __restrict__ in, bf16* __restrict__ out, int n4) {
  int stride = gridDim.x * blockDim.x;
  for (int i = blockIdx.x * blockDim.x + threadIdx.x; i < n4; i += stride) {
    float4 v = reinterpret_cast<const float4*>(in)[i];
    bf16x4v o;
    o[0] = (bf16)v.x; o[1] = (bf16)v.y; o[2] = (bf16)v.z; o[3] = (bf16)v.w;
    reinterpret_cast<bf16x4v*>(out)[i] = o;
  }
}

// ---------------- omega = sigmoid((x . w_omega + b)/16), one block per row ----------------
__global__ void omega_kernel(const float* __restrict__ x, const float* __restrict__ w_om,
                             const float* __restrict__ b_om, float* __restrict__ omega) {
  int row = blockIdx.x;
  const float4* xr = reinterpret_cast<const float4*>(x + (size_t)row * NC);
  const float4* wr = reinterpret_cast<const float4*>(w_om);
  float sum = 0.f;
  for (int i = threadIdx.x; i < NC/4; i += 256) {
    float4 a = xr[i], b = wr[i];
    sum += a.x*b.x + a.y*b.y + a.z*b.z + a.w*b.w;
  }
  for (int m = 32; m; m >>= 1) sum += __shfl_xor(sum, m);
  __shared__ float wsum[4];
  if ((threadIdx.x & 63) == 0) wsum[threadIdx.x >> 6] = sum;
  __syncthreads();
  if (threadIdx.x == 0) {
    float d = wsum[0] + wsum[1] + wsum[2] + wsum[3] + b_om[0];
    omega[row] = 1.f / (1.f + expf(-d * (1.f/16.f)));
  }
}

// ---------------- exclusive cumsum over T per batch (fp64 accumulation) ----------------
__global__ void scan_kernel(const float* __restrict__ omega, float* __restrict__ phi) {
  int b = blockIdx.x;
  const float* om = omega + (size_t)b * NT;
  float* ph = phi + (size_t)b * NT;
  int t = threadIdx.x;
  float v[8]; float s = 0.f;
  #pragma unroll
  for (int j = 0; j < 8; j++) { v[j] = om[t*8 + j]; s += v[j]; }
  __shared__ float totals[256];
  __shared__ double base_sh[256];
  totals[t] = s;
  __syncthreads();
  if (t == 0) {
    double run = 0.0;
    for (int i = 0; i < 256; i++) { base_sh[i] = run; run += (double)totals[i]; }
  }
  __syncthreads();
  double run = base_sh[t];
  #pragma unroll
  for (int j = 0; j < 8; j++) { ph[t*8 + j] = (float)run; run += (double)v[j]; }
}

// ---------------- cos/sin table: [row][dd], dd in 0..63 ----------------
__global__ void sincos_kernel(const float* __restrict__ phi, const float* __restrict__ log_freq,
                              float* __restrict__ cos_t, float* __restrict__ sin_t) {
  int i = blockIdx.x * 256 + threadIdx.x;   // < NROW*64
  int row = i >> 6, dd = i & 63;
  float f = expf(log_freq[dd]);
  float a = phi[row] * f;
  float si, co;
  sincosf(a, &si, &co);
  cos_t[i] = co;
  sin_t[i] = si;
}

// ---------------- 256x256 8-phase GEMM: C[m][n] = sum_k A[m][k]*B[n][k] ----------------
// 512 threads = 8 waves (4M x 2N), per-wave 64x128 output, BK=64, LDS 128KB dbuf.
// XOR-swizzled LDS (col ^= (row&7)<<4) via pre-swizzled global source (linear GLD dest).
// MODE 0: rotate+rmsnorm epilogue, bf16 out (q/k) | MODE 1: bf16 transposed Vt out | MODE 2: fp32 out
template<int MODE>
__global__ __launch_bounds__(512, 2)
void gemm256(const bf16* __restrict__ Ag, const bf16* __restrict__ Bg,
             void* __restrict__ Cout,
             const float* __restrict__ cos_t, const float* __restrict__ sin_t,
             const float* __restrict__ gamma) {
  constexpr int NKT = NC / 64;   // 32 K-tiles
  __shared__ bf16 Als[2][256 * 64];
  __shared__ bf16 Bls[2][256 * 64];
  const int t = threadIdx.x;
  const int lane = t & 63, lg = lane >> 4, l15 = lane & 15;
  const int wid = t >> 6, wm = wid >> 1, wn = wid & 1;
  // bijective XCD swizzle: 256 blocks, 8 XCDs, 32 consecutive work-ids per XCD
  const int bid = blockIdx.x;
  const int wg = (bid & 7) * 32 + (bid >> 3);
  const int m0 = (wg >> 3) * 256, n0 = (wg & 7) * 256;

  const size_t K2 = (size_t)NC * 2;
  // staging: thread t covers LDS bytes t*16 (+8KB strides); row=t>>3, slot col=(t&7)*16,
  // source col pre-swizzled by ((row&7)<<4)
  const int scol = ((t & 7) * 16) ^ (((t >> 3) & 7) << 4);
  const char* aS = (const char*)Ag + (size_t)(m0 + (t >> 3)) * K2 + scol;
  const char* bS = (const char*)Bg + (size_t)(n0 + (t >> 3)) * K2 + scol;

  const int colk0 = (lg * 16) ^ ((l15 & 7) << 4);
  const int colk[2] = { colk0, colk0 ^ 64 };
  const int arow = (wm * 64 + l15) * 128;    // byte base of this wave's A rows
  const int brow = (wn * 128 + l15) * 128;   // byte base of this wave's B rows

  f32x4 acc[4][8] = {};

#define STAGE_TA(kt, d) do { \
    const char* sa_ = aS + (size_t)(kt) * 128; \
    char* da_ = (char*)&Als[d][0] + t * 16; \
    GLD16(sa_,            da_); \
    GLD16(sa_ +  64*K2,   da_ + 8192); \
    GLD16(sa_ + 128*K2,   da_ + 16384); \
    GLD16(sa_ + 192*K2,   da_ + 24576); \
  } while(0)
#define STAGE_TB(kt, d) do { \
    const char* sb_ = bS + (size_t)(kt) * 128; \
    char* db_ = (char*)&Bls[d][0] + t * 16; \
    GLD16(sb_,            db_); \
    GLD16(sb_ +  64*K2,   db_ + 8192); \
    GLD16(sb_ + 128*K2,   db_ + 16384); \
    GLD16(sb_ + 192*K2,   db_ + 24576); \
  } while(0)

  STAGE_TA(0, 0); STAGE_TB(0, 0);
  asm volatile("s_waitcnt vmcnt(0)" ::: "memory");
  __builtin_amdgcn_s_barrier();
  asm volatile("" ::: "memory");

  bf16x8 aC[2][2], bC[4][2];
  for (int kt = 0; kt < NKT; kt++) {
    const int d = kt & 1;
    const char* Ab = (const char*)&Als[d][0];
    const char* Bb = (const char*)&Bls[d][0];
    const bool pf = (kt + 1 < NKT);

    // ---- ph1: read A(M0)+B(N0); stage A(next); MFMA M0N0 ----
    #pragma unroll
    for (int i = 0; i < 2; i++)
      #pragma unroll
      for (int kk = 0; kk < 2; kk++)
        aC[i][kk] = *(const bf16x8*)(Ab + arow + (i*16)*128 + colk[kk]);
    #pragma unroll
    for (int j = 0; j < 4; j++)
      #pragma unroll
      for (int kk = 0; kk < 2; kk++)
        bC[j][kk] = *(const bf16x8*)(Bb + brow + (j*16)*128 + colk[kk]);
    if (pf) STAGE_TA(kt+1, d^1);
    __builtin_amdgcn_s_barrier();
    asm volatile("s_waitcnt lgkmcnt(0)");
    __builtin_amdgcn_s_setprio(1);
    #pragma unroll
    for (int kk = 0; kk < 2; kk++)
      #pragma unroll
      for (int i = 0; i < 2; i++)
        #pragma unroll
        for (int j = 0; j < 4; j++)
          acc[i][j] = __builtin_amdgcn_mfma_f32_16x16x32_bf16(aC[i][kk], bC[j][kk], acc[i][j], 0,0,0);
    __builtin_amdgcn_s_setprio(0);

    // ---- ph2: read A(M1); stage B(next); MFMA M1N0 ----
    #pragma unroll
    for (int i = 0; i < 2; i++)
      #pragma unroll
      for (int kk = 0; kk < 2; kk++)
        aC[i][kk] = *(const bf16x8*)(Ab + arow + ((32 + i*16))*128 + colk[kk]);
    if (pf) STAGE_TB(kt+1, d^1);
    __builtin_amdgcn_s_barrier();
    asm volatile("s_waitcnt lgkmcnt(0)");
    __builtin_amdgcn_s_setprio(1);
    #pragma unroll
    for (int kk = 0; kk < 2; kk++)
      #pragma unroll
      for (int i = 0; i < 2; i++)
        #pragma unroll
        for (int j = 0; j < 4; j++)
          acc[2+i][j] = __builtin_amdgcn_mfma_f32_16x16x32_bf16(aC[i][kk], bC[j][kk], acc[2+i][j], 0,0,0);
    __builtin_amdgcn_s_setprio(0);

    // ---- ph3: read B(N1); MFMA M1N1 ----
    #pragma unroll
    for (int j = 0; j < 4; j++)
      #pragma unroll
      for (int kk = 0; kk < 2; kk++)
        bC[j][kk] = *(const bf16x8*)(Bb + brow + ((64 + j*16))*128 + colk[kk]);
    __builtin_amdgcn_s_barrier();
    asm volatile("s_waitcnt lgkmcnt(0)");
    __builtin_amdgcn_s_setprio(1);
    #pragma unroll
    for (int kk = 0; kk < 2; kk++)
      #pragma unroll
      for (int i = 0; i < 2; i++)
        #pragma unroll
        for (int j = 0; j < 4; j++)
          acc[2+i][4+j] = __builtin_amdgcn_mfma_f32_16x16x32_bf16(aC[i][kk], bC[j][kk], acc[2+i][4+j], 0,0,0);
    __builtin_amdgcn_s_setprio(0);

    // ---- ph4: re-read A(M0); MFMA M0N1 ----
    #pragma unroll
    for (int i = 0; i < 2; i++)
      #pragma unroll
      for (int kk = 0; kk < 2; kk++)
        aC[i][kk] = *(const bf16x8*)(Ab + arow + (i*16)*128 + colk[kk]);
    __builtin_amdgcn_s_barrier();
    asm volatile("s_waitcnt lgkmcnt(0)");
    __builtin_amdgcn_s_setprio(1);
    #pragma unroll
    for (int kk = 0; kk < 2; kk++)
      #pragma unroll
      for (int i = 0; i < 2; i++)
        #pragma unroll
        for (int j = 0; j < 4; j++)
          acc[i][4+j] = __builtin_amdgcn_mfma_f32_16x16x32_bf16(aC[i][kk], bC[j][kk], acc[i][4+j], 0,0,0);
    __builtin_amdgcn_s_setprio(0);

    // ---- tile boundary: next tile fully staged before reads ----
    asm volatile("s_waitcnt vmcnt(0)" ::: "memory");
    __builtin_amdgcn_s_barrier();
    asm volatile("" ::: "memory");
  }
#undef STAGE_TA
#undef STAGE_TB

  // ---------------- epilogues ----------------
  if constexpr (MODE == 0) {
    bf16* out = (bf16*)Cout;
    #pragma unroll
    for (int mi = 0; mi < 4; mi++) {
      #pragma unroll
      for (int r = 0; r < 4; r++) {
        int m = m0 + wm*64 + mi*16 + lg*4 + r;
        float ss = 0.f;
        #pragma unroll
        for (int nj = 0; nj < 8; nj++) { float v = acc[mi][nj][r]; ss += v*v; }
        ss += __shfl_xor(ss, 1); ss += __shfl_xor(ss, 2);
        ss += __shfl_xor(ss, 4); ss += __shfl_xor(ss, 8);
        float scale = rsqrtf(ss * (1.f/128.f) + 1e-5f);
        size_t rowb = (size_t)m * NC + n0 + wn*128;
        size_t tabb = (size_t)m * 64;
        #pragma unroll
        for (int nj = 0; nj < 4; nj++) {
          int dd = nj*16 + l15;
          float c = cos_t[tabb + dd];
          float s = sin_t[tabb + dd];
          float t1 = acc[mi][nj][r], t2 = acc[mi][nj+4][r];
          float o1 = (t1*c + t2*s) * scale * gamma[dd];
          float o2 = (t2*c - t1*s) * scale * gamma[dd + 64];
          out[rowb + dd] = (bf16)o1;
          out[rowb + dd + 64] = (bf16)o2;
        }
      }
    }
  } else if constexpr (MODE == 1) {
    // transposed write: Vt[b][h][d][t], t fastest
    bf16* vt = (bf16*)Cout;
    const int h = (n0 + wn*128) >> 7;
    #pragma unroll
    for (int mi = 0; mi < 4; mi++) {
      #pragma unroll
      for (int r = 0; r < 4; r++) {
        int m = m0 + wm*64 + mi*16 + lg*4 + r;
        int bidx = m >> 11, tt = m & (NT-1);
        size_t hb = (((size_t)bidx * NH + h) * ND) * NT + tt;
        #pragma unroll
        for (int nj = 0; nj < 8; nj++) {
          int d = nj*16 + l15;
          vt[hb + (size_t)d * NT] = (bf16)acc[mi][nj][r];
        }
      }
    }
  } else {
    float* out = (float*)Cout;
    #pragma unroll
    for (int mi = 0; mi < 4; mi++) {
      #pragma unroll
      for (int r = 0; r < 4; r++) {
        int m = m0 + wm*64 + mi*16 + lg*4 + r;
        size_t rowb = (size_t)m * NC + n0 + wn*128;
        #pragma unroll
        for (int nj = 0; nj < 8; nj++)
          out[rowb + nj*16 + l15] = acc[mi][nj][r];
      }
    }
  }
}

// ---------------- causal flash attention (unchanged from round 2) ----------------
// grid: (B*H, T/128), block 256 (4 waves x 32 q-rows), KV tile = 64
__global__ __launch_bounds__(256, 2)
void fa_kernel(const bf16* __restrict__ Qg, const bf16* __restrict__ Kg,
               const bf16* __restrict__ Vt, bf16* __restrict__ Og) {
  __shared__ bf16 Kls[64 * 128];
  __shared__ bf16 Vls[128 * 64];
  __shared__ bf16 Pls[4][32 * 68];   // per-wave P [q][kv], stride 68 elems (136B)
  const int t = threadIdx.x, w = t >> 6, lane = t & 63, lg = lane >> 4, l15 = lane & 15;
  const int bh = blockIdx.x;
  const int qb = (gridDim.y - 1) - blockIdx.y;   // big blocks dispatch first
  const size_t qkbase = (size_t)(bh >> 4) * NT * NC + (size_t)(bh & 15) * ND;
  const size_t vbase  = (size_t)bh * ND * NT;
  const int q0 = qb * 128 + w * 32;
  const float sc2 = 0.12751743f;   // log2(e)/sqrt(128)

  bf16x8 qf[2][4];
  #pragma unroll
  for (int mt = 0; mt < 2; mt++)
    #pragma unroll
    for (int kc = 0; kc < 4; kc++)
      qf[mt][kc] = *reinterpret_cast<const bf16x8*>(
          Qg + qkbase + (size_t)(q0 + mt*16 + l15) * NC + kc*32 + lg*8);

  f32x4 oacc[2][8] = {};
  float m_run[2][4], l_run[2][4];
  #pragma unroll
  for (int mt = 0; mt < 2; mt++)
    #pragma unroll
    for (int r = 0; r < 4; r++) { m_run[mt][r] = -1e30f; l_run[mt][r] = 0.f; }

  const int kinS = ((t & 15) * 16) ^ (((t >> 4) & 7) << 4);
  const char* ksrc0 = (const char*)(Kg + qkbase) + (size_t)(t >> 4) * (NC*2) + kinS;
  char* kdst0 = (char*)Kls + t * 16;
  const int vinS = ((t & 7) * 16) ^ (((t >> 3) & 7) << 4);
  const char* vsrc0 = (const char*)(Vt + vbase) + (size_t)(t >> 3) * (NT*2) + vinS;
  char* vdst0 = (char*)Vls + t * 16;

  const int nfull = 2 * qb;
  const int ntiles = 2 * qb + 2;

  for (int kt = 0; kt < ntiles; kt++) {
    const int kv0 = kt * 64;
    __syncthreads();
    {
      const char* ks = ksrc0 + (size_t)kv0 * (NC*2);
      const char* vs = vsrc0 + kv0 * 2;
      #pragma unroll
      for (int i = 0; i < 4; i++) {
        GLD16(ks + (size_t)i * 16 * NC * 2, kdst0 + i * 4096);
        GLD16(vs + (size_t)i * 32 * NT * 2, vdst0 + i * 4096);
      }
    }
    __syncthreads();

    if (q0 + 31 >= kv0) {
      f32x4 s[2][4] = {};
      __builtin_amdgcn_s_setprio(1);
      #pragma unroll
      for (int kc = 0; kc < 4; kc++) {
        bf16x8 kf[4];
        const int swz = ((kc*64 + lg*16) ^ ((l15 & 7) << 4));
        #pragma unroll
        for (int nt = 0; nt < 4; nt++)
          kf[nt] = *reinterpret_cast<const bf16x8*>((const char*)Kls + (nt*16 + l15) * 256 + swz);
        #pragma unroll
        for (int mt = 0; mt < 2; mt++)
          #pragma unroll
          for (int nt = 0; nt < 4; nt++)
            s[mt][nt] = __builtin_amdgcn_mfma_f32_16x16x32_bf16(qf[mt][kc], kf[nt], s[mt][nt], 0, 0, 0);
      }
      __builtin_amdgcn_s_setprio(0);

      #pragma unroll
      for (int mt = 0; mt < 2; mt++)
        #pragma unroll
        for (int nt = 0; nt < 4; nt++) {
          f32x4 v = s[mt][nt];
          v[0] *= sc2; v[1] *= sc2; v[2] *= sc2; v[3] *= sc2;
          s[mt][nt] = v;
        }
      if (kt >= nfull) {
        #pragma unroll
        for (int mt = 0; mt < 2; mt++)
          #pragma unroll
          for (int nt = 0; nt < 4; nt++) {
            int kv = kv0 + nt*16 + l15;
            #pragma unroll
            for (int r = 0; r < 4; r++)
              if (kv > q0 + mt*16 + lg*4 + r) s[mt][nt][r] = -1e30f;
          }
      }

      float tmax[2][4];
      #pragma unroll
      for (int mt = 0; mt < 2; mt++)
        #pragma unroll
        for (int r = 0; r < 4; r++) {
          float tm = fmaxf(fmaxf(s[mt][0][r], s[mt][1][r]), fmaxf(s[mt][2][r], s[mt][3][r]));
          tm = fmaxf(tm, __shfl_xor(tm, 1));
          tm = fmaxf(tm, __shfl_xor(tm, 2));
          tm = fmaxf(tm, __shfl_xor(tm, 4));
          tm = fmaxf(tm, __shfl_xor(tm, 8));
          tmax[mt][r] = tm;
        }

      int ok = 1;
      #pragma unroll
      for (int mt = 0; mt < 2; mt++)
        #pragma unroll
        for (int r = 0; r < 4; r++) ok &= (tmax[mt][r] <= m_run[mt][r]);
      if (!__all(ok)) {
        #pragma unroll
        for (int mt = 0; mt < 2; mt++) {
          f32x4 alv;
          #pragma unroll
          for (int r = 0; r < 4; r++) {
            float mn = fmaxf(m_run[mt][r], tmax[mt][r]);
            float a = exp2f(m_run[mt][r] - mn);
            m_run[mt][r] = mn;
            l_run[mt][r] *= a;
            alv[r] = a;
          }
          #pragma unroll
          for (int dt = 0; dt < 8; dt++) {
            f32x4 o = oacc[mt][dt];
            o[0] *= alv[0]; o[1] *= alv[1]; o[2] *= alv[2]; o[3] *= alv[3];
            oacc[mt][dt] = o;
          }
        }
      }

      bf16* pw = &Pls[w][0];
      #pragma unroll
      for (int mt = 0; mt < 2; mt++)
        #pragma unroll
        for (int r = 0; r < 4; r++) {
          float p0 = exp2f(s[mt][0][r] - m_run[mt][r]);
          float p1 = exp2f(s[mt][1][r] - m_run[mt][r]);
          float p2 = exp2f(s[mt][2][r] - m_run[mt][r]);
          float p3 = exp2f(s[mt][3][r] - m_run[mt][r]);
          float rs = (p0 + p1) + (p2 + p3);
          rs += __shfl_xor(rs, 1); rs += __shfl_xor(rs, 2);
          rs += __shfl_xor(rs, 4); rs += __shfl_xor(rs, 8);
          l_run[mt][r] += rs;
          int qrow = mt*16 + lg*4 + r;
          pw[qrow*68 +      l15] = (bf16)p0;
          pw[qrow*68 + 16 + l15] = (bf16)p1;
          pw[qrow*68 + 32 + l15] = (bf16)p2;
          pw[qrow*68 + 48 + l15] = (bf16)p3;
        }

      bf16x8 pf[2][2];
      #pragma unroll
      for (int mt = 0; mt < 2; mt++)
        #pragma unroll
        for (int kc2 = 0; kc2 < 2; kc2++)
          pf[mt][kc2] = *reinterpret_cast<const bf16x8*>(
              (const char*)pw + (mt*16 + l15) * 136 + kc2*64 + lg*16);
      __builtin_amdgcn_s_setprio(1);
      #pragma unroll
      for (int kc2 = 0; kc2 < 2; kc2++) {
        const int swz = ((kc2*64 + lg*16) ^ ((l15 & 7) << 4));
        #pragma unroll
        for (int dt = 0; dt < 8; dt++) {
          bf16x8 vf = *reinterpret_cast<const bf16x8*>((const char*)Vls + (dt*16 + l15) * 128 + swz);
          #pragma unroll
          for (int mt = 0; mt < 2; mt++)
            oacc[mt][dt] = __builtin_amdgcn_mfma_f32_16x16x32_bf16(pf[mt][kc2], vf, oacc[mt][dt], 0, 0, 0);
        }
      }
      __builtin_amdgcn_s_setprio(0);
    }
  }

  #pragma unroll
  for (int mt = 0; mt < 2; mt++)
    #pragma unroll
    for (int r = 0; r < 4; r++) {
      float inv = 1.f / l_run[mt][r];
      size_t orow = qkbase + (size_t)(q0 + mt*16 + lg*4 + r) * NC;
      #pragma unroll
      for (int dt = 0; dt < 8; dt++)
        Og[orow + dt*16 + l15] = (bf16)(oacc[mt][dt][r] * inv);
    }
}

// ---------------- host launch ----------------
extern "C" void kernel_launch(void* const* d_in, const int* in_sizes, int n_in,
                              void* d_out, int out_size, void* d_ws, size_t ws_size,
                              hipStream_t stream) {
  (void)in_sizes; (void)n_in; (void)out_size; (void)ws_size;
  const float* x       = (const float*)d_in[0];
  const float* Wq      = (const float*)d_in[1];
  const float* Wk      = (const float*)d_in[2];
  const float* Wv      = (const float*)d_in[3];
  const float* Wo      = (const float*)d_in[4];
  const float* w_omega = (const float*)d_in[5];
  const float* b_omega = (const float*)d_in[6];
  const float* log_freq= (const float*)d_in[7];
  const float* q_gamma = (const float*)d_in[8];
  const float* k_gamma = (const float*)d_in[9];

  char* p = (char*)d_ws;
  auto alloc = [&](size_t bytes) { void* r = (void*)p; p += (bytes + 255) & ~(size_t)255; return r; };
  bf16* xb   = (bf16*)alloc((size_t)NROW * NC * 2);
  bf16* wqb  = (bf16*)alloc((size_t)NC * NC * 2);
  bf16* wkb  = (bf16*)alloc((size_t)NC * NC * 2);
  bf16* wvb  = (bf16*)alloc((size_t)NC * NC * 2);
  bf16* wob  = (bf16*)alloc((size_t)NC * NC * 2);
  bf16* qb   = (bf16*)alloc((size_t)NROW * NC * 2);
  bf16* kb   = (bf16*)alloc((size_t)NROW * NC * 2);
  bf16* vt   = (bf16*)alloc((size_t)NROW * NC * 2);  // transposed V: [B][H][D][T]
  bf16* ob   = (bf16*)alloc((size_t)NROW * NC * 2);
  float* omega = (float*)alloc((size_t)NROW * 4);
  float* phi   = (float*)alloc((size_t)NROW * 4);
  float* cos_t = (float*)alloc((size_t)NROW * 64 * 4);
  float* sin_t = (float*)alloc((size_t)NROW * 64 * 4);

  cvt_kernel<<<4096, 256, 0, stream>>>(x, xb, NROW * NC / 4);
  cvt_kernel<<<2048, 256, 0, stream>>>(Wq, wqb, NC * NC / 4);
  cvt_kernel<<<2048, 256, 0, stream>>>(Wk, wkb, NC * NC / 4);
  cvt_kernel<<<2048, 256, 0, stream>>>(Wv, wvb, NC * NC / 4);
  cvt_kernel<<<2048, 256, 0, stream>>>(Wo, wob, NC * NC / 4);
  omega_kernel<<<NROW, 256, 0, stream>>>(x, w_omega, b_omega, omega);
  scan_kernel<<<NB, 256, 0, stream>>>(omega, phi);
  sincos_kernel<<<NROW * 64 / 256, 256, 0, stream>>>(phi, log_freq, cos_t, sin_t);

  gemm256<0><<<256, 512, 0, stream>>>(xb, wqb, qb, cos_t, sin_t, q_gamma);
  gemm256<0><<<256, 512, 0, stream>>>(xb, wkb, kb, cos_t, sin_t, k_gamma);
  gemm256<1><<<256, 512, 0, stream>>>(xb, wvb, vt, nullptr, nullptr, nullptr);

  fa_kernel<<<dim3(NB * NH, NT / 128), 256, 0, stream>>>(qb, kb, vt, ob);

  gemm256<2><<<256, 512, 0, stream>>>(ob, wob, d_out, nullptr, nullptr, nullptr);
}

// Round 4
// 509.100 us; speedup vs baseline: 1.5969x; 1.0412x over previous
//
#include <hip/hip_runtime.h>
#include <math.h>

typedef __bf16 bf16;
typedef __bf16 bf16x8 __attribute__((ext_vector_type(8)));
typedef __bf16 bf16x4v __attribute__((ext_vector_type(4)));
typedef float f32x4 __attribute__((ext_vector_type(4)));

#define NB 4
#define NT 2048
#define NC 2048
#define NH 16
#define ND 128
#define NROW (NB*NT)   // 8192

#define GLD16(g, l) __builtin_amdgcn_global_load_lds( \
    (__attribute__((address_space(1))) void*)(g), \
    (__attribute__((address_space(3))) void*)(l), 16, 0, 0)

// ---------------- fp32 -> bf16 convert ----------------
__global__ void cvt_kernel(const float* __restrict__ in, bf16* __restrict__ out, int n4) {
  int stride = gridDim.x * blockDim.x;
  for (int i = blockIdx.x * blockDim.x + threadIdx.x; i < n4; i += stride) {
    float4 v = reinterpret_cast<const float4*>(in)[i];
    bf16x4v o;
    o[0] = (bf16)v.x; o[1] = (bf16)v.y; o[2] = (bf16)v.z; o[3] = (bf16)v.w;
    reinterpret_cast<bf16x4v*>(out)[i] = o;
  }
}

// ---------------- omega = sigmoid((x . w_omega + b)/16), one block per row ----------------
__global__ void omega_kernel(const float* __restrict__ x, const float* __restrict__ w_om,
                             const float* __restrict__ b_om, float* __restrict__ omega) {
  int row = blockIdx.x;
  const float4* xr = reinterpret_cast<const float4*>(x + (size_t)row * NC);
  const float4* wr = reinterpret_cast<const float4*>(w_om);
  float sum = 0.f;
  for (int i = threadIdx.x; i < NC/4; i += 256) {
    float4 a = xr[i], b = wr[i];
    sum += a.x*b.x + a.y*b.y + a.z*b.z + a.w*b.w;
  }
  for (int m = 32; m; m >>= 1) sum += __shfl_xor(sum, m);
  __shared__ float wsum[4];
  if ((threadIdx.x & 63) == 0) wsum[threadIdx.x >> 6] = sum;
  __syncthreads();
  if (threadIdx.x == 0) {
    float d = wsum[0] + wsum[1] + wsum[2] + wsum[3] + b_om[0];
    omega[row] = 1.f / (1.f + expf(-d * (1.f/16.f)));
  }
}

// ---------------- exclusive cumsum over T per batch (fp64 accumulation) ----------------
__global__ void scan_kernel(const float* __restrict__ omega, float* __restrict__ phi) {
  int b = blockIdx.x;
  const float* om = omega + (size_t)b * NT;
  float* ph = phi + (size_t)b * NT;
  int t = threadIdx.x;
  float v[8]; float s = 0.f;
  #pragma unroll
  for (int j = 0; j < 8; j++) { v[j] = om[t*8 + j]; s += v[j]; }
  __shared__ float totals[256];
  __shared__ double base_sh[256];
  totals[t] = s;
  __syncthreads();
  if (t == 0) {
    double run = 0.0;
    for (int i = 0; i < 256; i++) { base_sh[i] = run; run += (double)totals[i]; }
  }
  __syncthreads();
  double run = base_sh[t];
  #pragma unroll
  for (int j = 0; j < 8; j++) { ph[t*8 + j] = (float)run; run += (double)v[j]; }
}

// ---------------- cos/sin table: [row][dd], dd in 0..63 ----------------
__global__ void sincos_kernel(const float* __restrict__ phi, const float* __restrict__ log_freq,
                              float* __restrict__ cos_t, float* __restrict__ sin_t) {
  int i = blockIdx.x * 256 + threadIdx.x;   // < NROW*64
  int row = i >> 6, dd = i & 63;
  float f = expf(log_freq[dd]);
  float a = phi[row] * f;
  float si, co;
  sincosf(a, &si, &co);
  cos_t[i] = co;
  sin_t[i] = si;
}

// ---------------- 256x256 GEMM: C[m][n] = sum_k A[m][k]*B[n][k] ----------------
// 512 threads = 8 waves (4M x 2N), per-wave 64x128 output, BK=64, LDS 128KB dbuf.
// MODE 0: rotate+rmsnorm epilogue (scaled by outscale), bf16 out (q/k)
// MODE 1: bf16 transposed Vt out | MODE 2: fp32 out
template<int MODE>
__global__ __launch_bounds__(512, 2)
void gemm256(const bf16* __restrict__ Ag, const bf16* __restrict__ Bg,
             void* __restrict__ Cout,
             const float* __restrict__ cos_t, const float* __restrict__ sin_t,
             const float* __restrict__ gamma, float outscale) {
  constexpr int NKT = NC / 64;   // 32 K-tiles
  __shared__ bf16 Als[2][256 * 64];
  __shared__ bf16 Bls[2][256 * 64];
  const int t = threadIdx.x;
  const int lane = t & 63, lg = lane >> 4, l15 = lane & 15;
  const int wid = t >> 6, wm = wid >> 1, wn = wid & 1;
  const int bid = blockIdx.x;
  const int wg = (bid & 7) * 32 + (bid >> 3);
  const int m0 = (wg >> 3) * 256, n0 = (wg & 7) * 256;

  const size_t K2 = (size_t)NC * 2;
  const int scol = ((t & 7) * 16) ^ (((t >> 3) & 7) << 4);
  const char* aS = (const char*)Ag + (size_t)(m0 + (t >> 3)) * K2 + scol;
  const char* bS = (const char*)Bg + (size_t)(n0 + (t >> 3)) * K2 + scol;

  const int colk0 = (lg * 16) ^ ((l15 & 7) << 4);
  const int colk[2] = { colk0, colk0 ^ 64 };
  const int arow = (wm * 64 + l15) * 128;
  const int brow = (wn * 128 + l15) * 128;

  f32x4 acc[4][8] = {};

#define STAGE_TA(kt, d) do { \
    const char* sa_ = aS + (size_t)(kt) * 128; \
    char* da_ = (char*)&Als[d][0] + t * 16; \
    GLD16(sa_,            da_); \
    GLD16(sa_ +  64*K2,   da_ + 8192); \
    GLD16(sa_ + 128*K2,   da_ + 16384); \
    GLD16(sa_ + 192*K2,   da_ + 24576); \
  } while(0)
#define STAGE_TB(kt, d) do { \
    const char* sb_ = bS + (size_t)(kt) * 128; \
    char* db_ = (char*)&Bls[d][0] + t * 16; \
    GLD16(sb_,            db_); \
    GLD16(sb_ +  64*K2,   db_ + 8192); \
    GLD16(sb_ + 128*K2,   db_ + 16384); \
    GLD16(sb_ + 192*K2,   db_ + 24576); \
  } while(0)

  STAGE_TA(0, 0); STAGE_TB(0, 0);
  asm volatile("s_waitcnt vmcnt(0)" ::: "memory");
  __builtin_amdgcn_s_barrier();
  asm volatile("" ::: "memory");

  bf16x8 aC[2][2], bC[4][2];
  for (int kt = 0; kt < NKT; kt++) {
    const int d = kt & 1;
    const char* Ab = (const char*)&Als[d][0];
    const char* Bb = (const char*)&Bls[d][0];
    const bool pf = (kt + 1 < NKT);

    #pragma unroll
    for (int i = 0; i < 2; i++)
      #pragma unroll
      for (int kk = 0; kk < 2; kk++)
        aC[i][kk] = *(const bf16x8*)(Ab + arow + (i*16)*128 + colk[kk]);
    #pragma unroll
    for (int j = 0; j < 4; j++)
      #pragma unroll
      for (int kk = 0; kk < 2; kk++)
        bC[j][kk] = *(const bf16x8*)(Bb + brow + (j*16)*128 + colk[kk]);
    if (pf) STAGE_TA(kt+1, d^1);
    __builtin_amdgcn_s_barrier();
    asm volatile("s_waitcnt lgkmcnt(0)");
    __builtin_amdgcn_s_setprio(1);
    #pragma unroll
    for (int kk = 0; kk < 2; kk++)
      #pragma unroll
      for (int i = 0; i < 2; i++)
        #pragma unroll
        for (int j = 0; j < 4; j++)
          acc[i][j] = __builtin_amdgcn_mfma_f32_16x16x32_bf16(aC[i][kk], bC[j][kk], acc[i][j], 0,0,0);
    __builtin_amdgcn_s_setprio(0);

    #pragma unroll
    for (int i = 0; i < 2; i++)
      #pragma unroll
      for (int kk = 0; kk < 2; kk++)
        aC[i][kk] = *(const bf16x8*)(Ab + arow + ((32 + i*16))*128 + colk[kk]);
    if (pf) STAGE_TB(kt+1, d^1);
    __builtin_amdgcn_s_barrier();
    asm volatile("s_waitcnt lgkmcnt(0)");
    __builtin_amdgcn_s_setprio(1);
    #pragma unroll
    for (int kk = 0; kk < 2; kk++)
      #pragma unroll
      for (int i = 0; i < 2; i++)
        #pragma unroll
        for (int j = 0; j < 4; j++)
          acc[2+i][j] = __builtin_amdgcn_mfma_f32_16x16x32_bf16(aC[i][kk], bC[j][kk], acc[2+i][j], 0,0,0);
    __builtin_amdgcn_s_setprio(0);

    #pragma unroll
    for (int j = 0; j < 4; j++)
      #pragma unroll
      for (int kk = 0; kk < 2; kk++)
        bC[j][kk] = *(const bf16x8*)(Bb + brow + ((64 + j*16))*128 + colk[kk]);
    __builtin_amdgcn_s_barrier();
    asm volatile("s_waitcnt lgkmcnt(0)");
    __builtin_amdgcn_s_setprio(1);
    #pragma unroll
    for (int kk = 0; kk < 2; kk++)
      #pragma unroll
      for (int i = 0; i < 2; i++)
        #pragma unroll
        for (int j = 0; j < 4; j++)
          acc[2+i][4+j] = __builtin_amdgcn_mfma_f32_16x16x32_bf16(aC[i][kk], bC[j][kk], acc[2+i][4+j], 0,0,0);
    __builtin_amdgcn_s_setprio(0);

    #pragma unroll
    for (int i = 0; i < 2; i++)
      #pragma unroll
      for (int kk = 0; kk < 2; kk++)
        aC[i][kk] = *(const bf16x8*)(Ab + arow + (i*16)*128 + colk[kk]);
    __builtin_amdgcn_s_barrier();
    asm volatile("s_waitcnt lgkmcnt(0)");
    __builtin_amdgcn_s_setprio(1);
    #pragma unroll
    for (int kk = 0; kk < 2; kk++)
      #pragma unroll
      for (int i = 0; i < 2; i++)
        #pragma unroll
        for (int j = 0; j < 4; j++)
          acc[i][4+j] = __builtin_amdgcn_mfma_f32_16x16x32_bf16(aC[i][kk], bC[j][kk], acc[i][4+j], 0,0,0);
    __builtin_amdgcn_s_setprio(0);

    asm volatile("s_waitcnt vmcnt(0)" ::: "memory");
    __builtin_amdgcn_s_barrier();
    asm volatile("" ::: "memory");
  }
#undef STAGE_TA
#undef STAGE_TB

  if constexpr (MODE == 0) {
    bf16* out = (bf16*)Cout;
    #pragma unroll
    for (int mi = 0; mi < 4; mi++) {
      #pragma unroll
      for (int r = 0; r < 4; r++) {
        int m = m0 + wm*64 + mi*16 + lg*4 + r;
        float ss = 0.f;
        #pragma unroll
        for (int nj = 0; nj < 8; nj++) { float v = acc[mi][nj][r]; ss += v*v; }
        ss += __shfl_xor(ss, 1); ss += __shfl_xor(ss, 2);
        ss += __shfl_xor(ss, 4); ss += __shfl_xor(ss, 8);
        float scale = rsqrtf(ss * (1.f/128.f) + 1e-5f) * outscale;
        size_t rowb = (size_t)m * NC + n0 + wn*128;
        size_t tabb = (size_t)m * 64;
        #pragma unroll
        for (int nj = 0; nj < 4; nj++) {
          int dd = nj*16 + l15;
          float c = cos_t[tabb + dd];
          float s = sin_t[tabb + dd];
          float t1 = acc[mi][nj][r], t2 = acc[mi][nj+4][r];
          float o1 = (t1*c + t2*s) * scale * gamma[dd];
          float o2 = (t2*c - t1*s) * scale * gamma[dd + 64];
          out[rowb + dd] = (bf16)o1;
          out[rowb + dd + 64] = (bf16)o2;
        }
      }
    }
  } else if constexpr (MODE == 1) {
    bf16* vt = (bf16*)Cout;
    const int h = (n0 + wn*128) >> 7;
    #pragma unroll
    for (int mi = 0; mi < 4; mi++) {
      #pragma unroll
      for (int r = 0; r < 4; r++) {
        int m = m0 + wm*64 + mi*16 + lg*4 + r;
        int bidx = m >> 11, tt = m & (NT-1);
        size_t hb = (((size_t)bidx * NH + h) * ND) * NT + tt;
        #pragma unroll
        for (int nj = 0; nj < 8; nj++) {
          int d = nj*16 + l15;
          vt[hb + (size_t)d * NT] = (bf16)acc[mi][nj][r];
        }
      }
    }
  } else {
    float* out = (float*)Cout;
    #pragma unroll
    for (int mi = 0; mi < 4; mi++) {
      #pragma unroll
      for (int r = 0; r < 4; r++) {
        int m = m0 + wm*64 + mi*16 + lg*4 + r;
        size_t rowb = (size_t)m * NC + n0 + wn*128;
        #pragma unroll
        for (int nj = 0; nj < 8; nj++)
          out[rowb + nj*16 + l15] = acc[mi][nj][r];
      }
    }
  }
}

// ---------------- causal flash attention v3 ----------------
// grid: (B*H, T/256), block 512 (8 waves x 32 q-rows), KV tile = 64, K/V double-buffered.
// Q pre-scaled by log2(e)/sqrt(128) at projection. l via MFMA-with-ones. THR=8 defer-rescale.
__global__ __launch_bounds__(512, 2)
void fa_kernel(const bf16* __restrict__ Qg, const bf16* __restrict__ Kg,
               const bf16* __restrict__ Vt, bf16* __restrict__ Og) {
  __shared__ bf16 Kls[2][64 * 128];
  __shared__ bf16 Vls[2][128 * 64];
  __shared__ bf16 Pls[8][32 * 68];
  const int t = threadIdx.x, w = t >> 6, lane = t & 63, lg = lane >> 4, l15 = lane & 15;
  const int bh = blockIdx.x;
  const int qb = (gridDim.y - 1) - blockIdx.y;   // big blocks dispatch first
  const size_t qkbase = (size_t)(bh >> 4) * NT * NC + (size_t)(bh & 15) * ND;
  const size_t vbase  = (size_t)bh * ND * NT;
  const int q0 = qb * 256 + w * 32;

  bf16x8 qf[2][4];
  #pragma unroll
  for (int mt = 0; mt < 2; mt++)
    #pragma unroll
    for (int kc = 0; kc < 4; kc++)
      qf[mt][kc] = *reinterpret_cast<const bf16x8*>(
          Qg + qkbase + (size_t)(q0 + mt*16 + l15) * NC + kc*32 + lg*8);

  f32x4 oacc[2][8] = {};
  f32x4 lacc[2] = {};
  float m_run[2][4];
  #pragma unroll
  for (int mt = 0; mt < 2; mt++)
    #pragma unroll
    for (int r = 0; r < 4; r++) m_run[mt][r] = -1e30f;

  bf16x8 vone;
  #pragma unroll
  for (int i = 0; i < 8; i++) vone[i] = (bf16)1.0f;

  // staging maps (XOR-swizzled source, linear LDS dest)
  const int kinS = ((t & 15) * 16) ^ (((t >> 4) & 7) << 4);
  const char* ksrc0 = (const char*)(Kg + qkbase) + (size_t)(t >> 4) * (NC*2) + kinS;
  const int vinS = ((t & 7) * 16) ^ (((t >> 3) & 7) << 4);
  const char* vsrc0 = (const char*)(Vt + vbase) + (size_t)(t >> 3) * (NT*2) + vinS;

#define STAGE(kt, d) do { \
    const char* ks_ = ksrc0 + (size_t)(kt) * 64 * (NC*2); \
    const char* vs_ = vsrc0 + (size_t)(kt) * 128; \
    char* kd_ = (char*)&Kls[d][0] + t * 16; \
    char* vd_ = (char*)&Vls[d][0] + t * 16; \
    GLD16(ks_,                        kd_); \
    GLD16(ks_ + (size_t)32 * NC * 2,  kd_ + 8192); \
    GLD16(vs_,                        vd_); \
    GLD16(vs_ + (size_t)64 * NT * 2,  vd_ + 8192); \
  } while(0)

  const int ntiles = 4 * qb + 4;
  STAGE(0, 0);
  __syncthreads();

  for (int kt = 0; kt < ntiles; kt++) {
    const int d = kt & 1;
    const int kv0 = kt * 64;
    if (kt + 1 < ntiles) STAGE(kt + 1, d ^ 1);

    if (q0 + 31 >= kv0) {
      // ---- S = Q K^T (log2-scaled, q pre-scaled) ----
      f32x4 s[2][4] = {};
      __builtin_amdgcn_s_setprio(1);
      #pragma unroll
      for (int kc = 0; kc < 4; kc++) {
        bf16x8 kf[4];
        const int swz = ((kc*64 + lg*16) ^ ((l15 & 7) << 4));
        #pragma unroll
        for (int nt = 0; nt < 4; nt++)
          kf[nt] = *reinterpret_cast<const bf16x8*>((const char*)&Kls[d][0] + (nt*16 + l15) * 256 + swz);
        #pragma unroll
        for (int mt = 0; mt < 2; mt++)
          #pragma unroll
          for (int nt = 0; nt < 4; nt++)
            s[mt][nt] = __builtin_amdgcn_mfma_f32_16x16x32_bf16(qf[mt][kc], kf[nt], s[mt][nt], 0, 0, 0);
      }
      __builtin_amdgcn_s_setprio(0);

      // ---- mask (diagonal region only) ----
      if (kv0 + 63 > q0) {
        #pragma unroll
        for (int mt = 0; mt < 2; mt++)
          #pragma unroll
          for (int nt = 0; nt < 4; nt++) {
            int kv = kv0 + nt*16 + l15;
            #pragma unroll
            for (int r = 0; r < 4; r++)
              if (kv > q0 + mt*16 + lg*4 + r) s[mt][nt][r] = -1e30f;
          }
      }

      // ---- row maxima ----
      float tmax[2][4];
      #pragma unroll
      for (int mt = 0; mt < 2; mt++)
        #pragma unroll
        for (int r = 0; r < 4; r++) {
          float tm = fmaxf(fmaxf(s[mt][0][r], s[mt][1][r]), fmaxf(s[mt][2][r], s[mt][3][r]));
          tm = fmaxf(tm, __shfl_xor(tm, 1));
          tm = fmaxf(tm, __shfl_xor(tm, 2));
          tm = fmaxf(tm, __shfl_xor(tm, 4));
          tm = fmaxf(tm, __shfl_xor(tm, 8));
          tmax[mt][r] = tm;
        }

      // ---- defer-rescale, THR=8 (in log2 domain) ----
      int ok = 1;
      #pragma unroll
      for (int mt = 0; mt < 2; mt++)
        #pragma unroll
        for (int r = 0; r < 4; r++) ok &= (tmax[mt][r] <= m_run[mt][r] + 8.0f);
      if (!__all(ok)) {
        #pragma unroll
        for (int mt = 0; mt < 2; mt++) {
          f32x4 alv;
          #pragma unroll
          for (int r = 0; r < 4; r++) {
            float mn = fmaxf(m_run[mt][r], tmax[mt][r]);
            alv[r] = exp2f(m_run[mt][r] - mn);
            m_run[mt][r] = mn;
          }
          #pragma unroll
          for (int dt = 0; dt < 8; dt++) {
            f32x4 o = oacc[mt][dt];
            o[0] *= alv[0]; o[1] *= alv[1]; o[2] *= alv[2]; o[3] *= alv[3];
            oacc[mt][dt] = o;
          }
          f32x4 lv = lacc[mt];
          lv[0] *= alv[0]; lv[1] *= alv[1]; lv[2] *= alv[2]; lv[3] *= alv[3];
          lacc[mt] = lv;
        }
      }

      // ---- P = exp2(s - m) -> LDS (row sums come free via ones-MFMA) ----
      bf16* pw = &Pls[w][0];
      #pragma unroll
      for (int mt = 0; mt < 2; mt++)
        #pragma unroll
        for (int r = 0; r < 4; r++) {
          float p0 = exp2f(s[mt][0][r] - m_run[mt][r]);
          float p1 = exp2f(s[mt][1][r] - m_run[mt][r]);
          float p2 = exp2f(s[mt][2][r] - m_run[mt][r]);
          float p3 = exp2f(s[mt][3][r] - m_run[mt][r]);
          int qrow = mt*16 + lg*4 + r;
          pw[qrow*68 +      l15] = (bf16)p0;
          pw[qrow*68 + 16 + l15] = (bf16)p1;
          pw[qrow*68 + 32 + l15] = (bf16)p2;
          pw[qrow*68 + 48 + l15] = (bf16)p3;
        }

      // ---- O += P V ; l += P 1 ----
      bf16x8 pf[2][2];
      #pragma unroll
      for (int mt = 0; mt < 2; mt++)
        #pragma unroll
        for (int kc2 = 0; kc2 < 2; kc2++)
          pf[mt][kc2] = *reinterpret_cast<const bf16x8*>(
              (const char*)pw + (mt*16 + l15) * 136 + kc2*64 + lg*16);
      __builtin_amdgcn_s_setprio(1);
      #pragma unroll
      for (int kc2 = 0; kc2 < 2; kc2++) {
        #pragma unroll
        for (int mt = 0; mt < 2; mt++)
          lacc[mt] = __builtin_amdgcn_mfma_f32_16x16x32_bf16(pf[mt][kc2], vone, lacc[mt], 0, 0, 0);
        const int swz = ((kc2*64 + lg*16) ^ ((l15 & 7) << 4));
        #pragma unroll
        for (int dt = 0; dt < 8; dt++) {
          bf16x8 vf = *reinterpret_cast<const bf16x8*>((const char*)&Vls[d][0] + (dt*16 + l15) * 128 + swz);
          #pragma unroll
          for (int mt = 0; mt < 2; mt++)
            oacc[mt][dt] = __builtin_amdgcn_mfma_f32_16x16x32_bf16(pf[mt][kc2], vf, oacc[mt][dt], 0, 0, 0);
        }
      }
      __builtin_amdgcn_s_setprio(0);
    }

    __syncthreads();   // drains staging (issued at loop top, hidden under compute)
  }
#undef STAGE

  // ---- epilogue ----
  #pragma unroll
  for (int mt = 0; mt < 2; mt++)
    #pragma unroll
    for (int r = 0; r < 4; r++) {
      float inv = 1.f / lacc[mt][r];
      size_t orow = qkbase + (size_t)(q0 + mt*16 + lg*4 + r) * NC;
      #pragma unroll
      for (int dt = 0; dt < 8; dt++)
        Og[orow + dt*16 + l15] = (bf16)(oacc[mt][dt][r] * inv);
    }
}

// ---------------- host launch ----------------
extern "C" void kernel_launch(void* const* d_in, const int* in_sizes, int n_in,
                              void* d_out, int out_size, void* d_ws, size_t ws_size,
                              hipStream_t stream) {
  (void)in_sizes; (void)n_in; (void)out_size; (void)ws_size;
  const float* x       = (const float*)d_in[0];
  const float* Wq      = (const float*)d_in[1];
  const float* Wk      = (const float*)d_in[2];
  const float* Wv      = (const float*)d_in[3];
  const float* Wo      = (const float*)d_in[4];
  const float* w_omega = (const float*)d_in[5];
  const float* b_omega = (const float*)d_in[6];
  const float* log_freq= (const float*)d_in[7];
  const float* q_gamma = (const float*)d_in[8];
  const float* k_gamma = (const float*)d_in[9];

  char* p = (char*)d_ws;
  auto alloc = [&](size_t bytes) { void* r = (void*)p; p += (bytes + 255) & ~(size_t)255; return r; };
  bf16* xb   = (bf16*)alloc((size_t)NROW * NC * 2);
  bf16* wqb  = (bf16*)alloc((size_t)NC * NC * 2);
  bf16* wkb  = (bf16*)alloc((size_t)NC * NC * 2);
  bf16* wvb  = (bf16*)alloc((size_t)NC * NC * 2);
  bf16* wob  = (bf16*)alloc((size_t)NC * NC * 2);
  bf16* qb   = (bf16*)alloc((size_t)NROW * NC * 2);
  bf16* kb   = (bf16*)alloc((size_t)NROW * NC * 2);
  bf16* vt   = (bf16*)alloc((size_t)NROW * NC * 2);  // transposed V: [B][H][D][T]
  bf16* ob   = (bf16*)alloc((size_t)NROW * NC * 2);
  float* omega = (float*)alloc((size_t)NROW * 4);
  float* phi   = (float*)alloc((size_t)NROW * 4);
  float* cos_t = (float*)alloc((size_t)NROW * 64 * 4);
  float* sin_t = (float*)alloc((size_t)NROW * 64 * 4);

  cvt_kernel<<<4096, 256, 0, stream>>>(x, xb, NROW * NC / 4);
  cvt_kernel<<<2048, 256, 0, stream>>>(Wq, wqb, NC * NC / 4);
  cvt_kernel<<<2048, 256, 0, stream>>>(Wk, wkb, NC * NC / 4);
  cvt_kernel<<<2048, 256, 0, stream>>>(Wv, wvb, NC * NC / 4);
  cvt_kernel<<<2048, 256, 0, stream>>>(Wo, wob, NC * NC / 4);
  omega_kernel<<<NROW, 256, 0, stream>>>(x, w_omega, b_omega, omega);
  scan_kernel<<<NB, 256, 0, stream>>>(omega, phi);
  sincos_kernel<<<NROW * 64 / 256, 256, 0, stream>>>(phi, log_freq, cos_t, sin_t);

  const float sc2 = 0.12751726f;   // log2(e)/sqrt(128), folded into q
  gemm256<0><<<256, 512, 0, stream>>>(xb, wqb, qb, cos_t, sin_t, q_gamma, sc2);
  gemm256<0><<<256, 512, 0, stream>>>(xb, wkb, kb, cos_t, sin_t, k_gamma, 1.0f);
  gemm256<1><<<256, 512, 0, stream>>>(xb, wvb, vt, nullptr, nullptr, nullptr, 1.0f);

  fa_kernel<<<dim3(NB * NH, NT / 256), 512, 0, stream>>>(qb, kb, vt, ob);

  gemm256<2><<<256, 512, 0, stream>>>(ob, wob, d_out, nullptr, nullptr, nullptr, 1.0f);
}